// Round 20
// baseline (250.337 us; speedup 1.0000x reference)
//
#include <hip/hip_runtime.h>
#include <hip/hip_bf16.h>
#include <math.h>

#define N_ROWS 65536
#define PSI    1024
#define DDIM   256

typedef _Float16       half8 __attribute__((ext_vector_type(8)));
typedef _Float16       half4 __attribute__((ext_vector_type(4)));
typedef float          f32x4 __attribute__((ext_vector_type(4)));

#define LOG2E 1.4426950408889634f

// Raw-instruction transcendentals (~1-2 ulp, negligible vs 3.8e-6 f16 floor).
#if __has_builtin(__builtin_amdgcn_sqrtf)
#define FSQRT(x) __builtin_amdgcn_sqrtf(x)
#else
#define FSQRT(x) sqrtf(x)
#endif
#if __has_builtin(__builtin_amdgcn_exp2f)
#define FEXP2(x) __builtin_amdgcn_exp2f(x)
#else
#define FEXP2(x) exp2f(x)
#endif
#if __has_builtin(__builtin_amdgcn_rcpf)
#define FRCP(x) __builtin_amdgcn_rcpf(x)
#else
#define FRCP(x) (1.0f / (x))
#endif

// ---------- async global->LDS, 16B per lane ----------
__device__ __forceinline__ void gload16(const void* g, void* l) {
    __builtin_amdgcn_global_load_lds(
        (const __attribute__((address_space(1))) unsigned int*)g,
        (__attribute__((address_space(3))) unsigned int*)l, 16, 0, 0);
}

// ---------- fused convert (X and S) + row norms + gsum init, grid-stride ---
__global__ __launch_bounds__(256) void k_convert_all(
    const float* __restrict__ X, const float* __restrict__ S,
    _Float16* __restrict__ Xh, _Float16* __restrict__ Sh,
    float* __restrict__ x2, float* __restrict__ s2,
    float* __restrict__ gsum)
{
    const int wib  = threadIdx.x >> 6;
    const int lane = threadIdx.x & 63;
    for (int u = blockIdx.x; u < 16640; u += 2048) {
        const float* in; _Float16* outh; float* nrm; int row;
        if (u < 16384) { in = X; outh = Xh; nrm = x2; row = u * 4 + wib; }
        else { in = S; outh = Sh; nrm = s2; row = (u - 16384) * 4 + wib; }
        const f32x4 v = __builtin_nontemporal_load(
            (const f32x4*)&in[(size_t)row * DDIM + lane * 4]);
        float s = v[0] * v[0] + v[1] * v[1] + v[2] * v[2] + v[3] * v[3];
        #pragma unroll
        for (int o = 32; o > 0; o >>= 1) s += __shfl_down(s, o);
        if (lane == 0) nrm[row] = s;
        half4 h;
        h[0] = (_Float16)v[0]; h[1] = (_Float16)v[1];
        h[2] = (_Float16)v[2]; h[3] = (_Float16)v[3];
        *(half4*)&outh[(size_t)row * DDIM + lane * 4] = h;
    }
    if (blockIdx.x == 0) {                    // re-init every call (graph replay)
        for (int i = threadIdx.x; i < PSI; i += 256) gsum[i] = 0.0f;
    }
}

// ---------- MFMA GEMM, 256x256 tile, 8-phase/K-tile, 4 col-tiles/block -----
// Grid 256 = 1 block/CU, single launch generation. Each block owns one
// 256-row band x all 4 col-tiles, pipelined ACROSS tiles: the empty staging
// slots at each tile's last K-tile (t=3) stage the NEXT tile's first
// buffers (A re-staged L2-hot -- same band; B advances to next 256 cols).
// Tile-boundary wait: MODE1 uses counted vmcnt(32) -- vmcnt retires in
// order, so the 8 staged loads (oldest) are guaranteed retired while up to
// 32 NT stores stream on under the next tile's compute. MODE0 (1 atomic,
// no store burst) and ct=0 use vmcnt(0). Epilogue barriers are lgkmcnt-only
// (don't drain the in-flight next-tile staging). s_sm is a DEDICATED array
// (the old As-alias would collide with in-flight staging).
// Swizzle both-sides: linear slot s of 128B row r holds global chunk
// s^(r&7); ds_read XORs the chunk (2-way banks = free).
// Shift-free softmax: u = exp2(-sqrt(max(x2+s2-2dot,0))*w*log2e) in
// [1e-13,1] -> no max-shift. Fast transcendentals.
// MODE 0: column sums of u -> atomicAdd into gsum.
// MODE 1: out = u * rcp(gsum[c])  (nontemporal, coalesced 64B lines).
template<int MODE>
__global__ __launch_bounds__(512, 2) void k_gemm(
    const _Float16* __restrict__ Xh, const _Float16* __restrict__ Sh,
    const float* __restrict__ x2, const float* __restrict__ s2,
    const float* __restrict__ w,
    float* __restrict__ gsum, float* __restrict__ out)
{
    __shared__ _Float16 As[2][2][128 * 64];   // 64 KB
    __shared__ _Float16 Bs[2][2][128 * 64];   // 64 KB
    __shared__ float    s_sm[256];            // MODE0 sums (dedicated, 1 KB)

    const int tid = threadIdx.x;
    const int wv  = tid >> 6;       // 0..7
    const int wr  = wv >> 2;        // M half (128 rows)
    const int wc  = wv & 3;         // N quarter (64 cols)
    const int l15 = tid & 15;
    const int l4  = (tid & 63) >> 4;

    // 256 blocks: XCD (b&7) owns 32 row-bands; 4 col-tiles per block
    const int rowb = (blockIdx.x & 7) * 32 + (blockIdx.x >> 3);   // 0..255
    const int row0 = rowb * 256;

    f32x4 acc[8][4];
    #pragma unroll
    for (int i = 0; i < 8; ++i)
        #pragma unroll
        for (int j = 0; j < 4; ++j) acc[i][j] = (f32x4){0.f, 0.f, 0.f, 0.f};

    const int grow = tid >> 3;           // 0..63
    const int gch  = (tid & 7) ^ (grow & 7);
    const _Float16* gA = Xh + (size_t)(row0 + grow) * DDIM + gch * 8;
    const _Float16* gB = Sh + (size_t)grow * DDIM + gch * 8;

    auto stageA = [&](int kt, int buf, int h) {
        #pragma unroll
        for (int rg = 0; rg < 2; ++rg)
            gload16(gA + (size_t)(h * 128 + rg * 64) * DDIM + kt * 64,
                    &As[buf][h][(rg * 64 + wv * 8) * 64]);
    };
    auto stageB = [&](int ct, int kt, int buf, int h) {
        #pragma unroll
        for (int rg = 0; rg < 2; ++rg)
            gload16(gB + (size_t)(ct * 256 + h * 128 + rg * 64) * DDIM + kt * 64,
                    &Bs[buf][h][(rg * 64 + wv * 8) * 64]);
    };

    const int qa0 = l15 * 64 + ((l4)     ^ (l15 & 7)) * 8;   // kk=0
    const int qa1 = l15 * 64 + ((4 + l4) ^ (l15 & 7)) * 8;   // kk=1
    const int bof = (wc & 1) * 4096;     // 64 rows into the B half

    half8 a[4][2], blo[2][2], bhi[2][2];
    auto loadA = [&](int cur, int hsel) {
        #pragma unroll
        for (int i = 0; i < 4; ++i) {
            a[i][0] = *(const half8*)&As[cur][wr][(hsel * 4 + i) * 1024 + qa0];
            a[i][1] = *(const half8*)&As[cur][wr][(hsel * 4 + i) * 1024 + qa1];
        }
    };
    auto loadB = [&](int cur, half8 b[2][2], int fnb) {
        #pragma unroll
        for (int jn = 0; jn < 2; ++jn) {
            b[jn][0] = *(const half8*)&Bs[cur][wc >> 1][bof + (fnb + jn) * 1024 + qa0];
            b[jn][1] = *(const half8*)&Bs[cur][wc >> 1][bof + (fnb + jn) * 1024 + qa1];
        }
    };
    auto mfmaQ = [&](half8 b[2][2], int fmb, int fnb) {
        __builtin_amdgcn_s_setprio(1);
        #pragma unroll
        for (int i = 0; i < 4; ++i)
            #pragma unroll
            for (int jn = 0; jn < 2; ++jn)
                #pragma unroll
                for (int kk = 0; kk < 2; ++kk)
                    acc[fmb + i][fnb + jn] = __builtin_amdgcn_mfma_f32_16x16x32_f16(
                        a[i][kk], b[jn][kk], acc[fmb + i][fnb + jn], 0, 0, 0);
        __builtin_amdgcn_s_setprio(0);
    };

    // x2 fixed for the whole block (one row-band)
    float4 x2r[8];
    #pragma unroll
    for (int fm = 0; fm < 8; ++fm)
        x2r[fm] = *(const float4*)&x2[row0 + wr * 128 + fm * 16 + l4 * 4];

    // ---- prologue: stage tile 0 (ct=0, kt=0) ----
    stageA(0, 0, 0); stageA(0, 0, 1); stageB(0, 0, 0, 0); stageB(0, 0, 0, 1);

    #pragma unroll 1
    for (int ct = 0; ct < 4; ++ct) {
        // boundary: staged loads (oldest, in-order retire) must be done;
        // MODE1 keeps <=32 NT stores in flight across the boundary.
        if (MODE == 0 || ct == 0)
            asm volatile("s_waitcnt vmcnt(0)\ns_barrier" ::: "memory");
        else
            asm volatile("s_waitcnt vmcnt(32)\ns_barrier" ::: "memory");

        #pragma unroll
        for (int t = 0; t < 4; ++t) {        // K = 4 x 64
            const int cur = t & 1, nxt = cur ^ 1;
            loadA(cur, 0); loadB(cur, blo, 0);
            if (t < 3) stageA(t + 1, nxt, 0);
            else if (ct < 3) stageA(0, nxt, 0);
            asm volatile("s_barrier" ::: "memory");
            mfmaQ(blo, 0, 0);
            asm volatile("s_barrier" ::: "memory");
            loadB(cur, bhi, 2);
            if (t < 3) stageA(t + 1, nxt, 1);
            else if (ct < 3) stageA(0, nxt, 1);
            asm volatile("s_barrier" ::: "memory");
            mfmaQ(bhi, 0, 2);
            asm volatile("s_barrier" ::: "memory");
            loadA(cur, 1);
            if (t < 3) stageB(ct, t + 1, nxt, 0);
            else if (ct < 3) stageB(ct + 1, 0, nxt, 0);
            asm volatile("s_barrier" ::: "memory");
            mfmaQ(bhi, 4, 2);
            asm volatile("s_barrier" ::: "memory");
            if (t < 3) stageB(ct, t + 1, nxt, 1);
            else if (ct < 3) stageB(ct + 1, 0, nxt, 1);
            asm volatile("s_barrier" ::: "memory");
            mfmaQ(blo, 4, 0);
            if (t < 3) asm volatile("s_waitcnt vmcnt(0)\ns_barrier" ::: "memory");
        }

        // ---- epilogue for ct (next tile's staging in flight) ----
        const int col0 = ct * 256;
        if (MODE == 0) {
            if (tid < 256) s_sm[tid] = 0.0f;
            asm volatile("s_waitcnt lgkmcnt(0)\ns_barrier" ::: "memory");
            #pragma unroll
            for (int fn = 0; fn < 4; ++fn) {
                const int cl = wc * 64 + fn * 16 + l15;
                const int c  = col0 + cl;
                const float s2c = s2[c], ww2 = w[c] * LOG2E;
                float s = 0.0f;
                #pragma unroll
                for (int fm = 0; fm < 8; ++fm) {
                    const float* xr = (const float*)&x2r[fm];
                    #pragma unroll
                    for (int j = 0; j < 4; ++j) {
                        float d2 = xr[j] + s2c - 2.0f * acc[fm][fn][j];
                        s += FEXP2(-FSQRT(fmaxf(d2, 0.0f)) * ww2);
                    }
                }
                s += __shfl_xor(s, 16);
                s += __shfl_xor(s, 32);
                if (l4 == 0) atomicAdd(&s_sm[cl], s);   // 2 waves (wr) contend
            }
            asm volatile("s_waitcnt lgkmcnt(0)\ns_barrier" ::: "memory");
            if (tid < 256) atomicAdd(&gsum[col0 + tid], s_sm[tid]);
        } else {
            #pragma unroll
            for (int fn = 0; fn < 4; ++fn) {
                const int c = col0 + wc * 64 + fn * 16 + l15;
                const float s2c = s2[c], ww2 = w[c] * LOG2E;
                const float rsc = FRCP(gsum[c]);
                #pragma unroll
                for (int fm = 0; fm < 8; ++fm) {
                    const float* xr = (const float*)&x2r[fm];
                    const int rbase = row0 + wr * 128 + fm * 16 + l4 * 4;
                    #pragma unroll
                    for (int j = 0; j < 4; ++j) {
                        float d2 = xr[j] + s2c - 2.0f * acc[fm][fn][j];
                        float u  = FEXP2(-FSQRT(fmaxf(d2, 0.0f)) * ww2) * rsc;
                        __builtin_nontemporal_store(u,
                            &out[(size_t)(rbase + j) * PSI + c]);
                    }
                }
            }
        }

        // reset accumulators for the next tile
        if (ct < 3) {
            #pragma unroll
            for (int i = 0; i < 8; ++i)
                #pragma unroll
                for (int j = 0; j < 4; ++j) acc[i][j] = (f32x4){0.f, 0.f, 0.f, 0.f};
        }
    }
}

extern "C" void kernel_launch(void* const* d_in, const int* in_sizes, int n_in,
                              void* d_out, int out_size, void* d_ws, size_t ws_size,
                              hipStream_t stream) {
    const float* X = (const float*)d_in[0];
    const float* S = (const float*)d_in[1];
    const float* w = (const float*)d_in[2];
    float* out = (float*)d_out;

    char* ws = (char*)d_ws;
    _Float16* Xh   = (_Float16*)(ws);                  // 33,554,432 B
    _Float16* Sh   = (_Float16*)(ws + 33554432);       //    524,288 B
    float*    x2   = (float*)   (ws + 34078720);       //    262,144 B
    float*    s2   = (float*)   (ws + 34340864);       //      4,096 B
    float*    gsum = (float*)   (ws + 34344960);       //      4,096 B

    k_convert_all<<<dim3(2048), dim3(256), 0, stream>>>(
        X, S, Xh, Sh, x2, s2, gsum);
    k_gemm<0><<<dim3(256), dim3(512), 0, stream>>>(
        Xh, Sh, x2, s2, w, gsum, nullptr);
    k_gemm<1><<<dim3(256), dim3(512), 0, stream>>>(
        Xh, Sh, x2, s2, w, gsum, out);
}

// Round 21
// 147.749 us; speedup vs baseline: 1.6943x; 1.6943x over previous
//
#include <hip/hip_runtime.h>
#include <hip/hip_bf16.h>
#include <math.h>

#define N_ROWS 65536
#define PSI    1024
#define DDIM   256

typedef _Float16       half8 __attribute__((ext_vector_type(8)));
typedef _Float16       half4 __attribute__((ext_vector_type(4)));
typedef float          f32x4 __attribute__((ext_vector_type(4)));

#define LOG2E 1.4426950408889634f

// Raw-instruction transcendentals (~1-2 ulp, negligible vs 3.8e-6 f16 floor).
#if __has_builtin(__builtin_amdgcn_sqrtf)
#define FSQRT(x) __builtin_amdgcn_sqrtf(x)
#else
#define FSQRT(x) sqrtf(x)
#endif
#if __has_builtin(__builtin_amdgcn_exp2f)
#define FEXP2(x) __builtin_amdgcn_exp2f(x)
#else
#define FEXP2(x) exp2f(x)
#endif
#if __has_builtin(__builtin_amdgcn_rcpf)
#define FRCP(x) __builtin_amdgcn_rcpf(x)
#else
#define FRCP(x) (1.0f / (x))
#endif

// ---------- async global->LDS, 16B per lane ----------
__device__ __forceinline__ void gload16(const void* g, void* l) {
    __builtin_amdgcn_global_load_lds(
        (const __attribute__((address_space(1))) unsigned int*)g,
        (__attribute__((address_space(3))) unsigned int*)l, 16, 0, 0);
}

// ---------- fused convert (X and S) + row norms + gsum init, grid-stride ---
__global__ __launch_bounds__(256) void k_convert_all(
    const float* __restrict__ X, const float* __restrict__ S,
    _Float16* __restrict__ Xh, _Float16* __restrict__ Sh,
    float* __restrict__ x2, float* __restrict__ s2,
    float* __restrict__ gsum)
{
    const int wib  = threadIdx.x >> 6;
    const int lane = threadIdx.x & 63;
    for (int u = blockIdx.x; u < 16640; u += 2048) {
        const float* in; _Float16* outh; float* nrm; int row;
        if (u < 16384) { in = X; outh = Xh; nrm = x2; row = u * 4 + wib; }
        else { in = S; outh = Sh; nrm = s2; row = (u - 16384) * 4 + wib; }
        const f32x4 v = __builtin_nontemporal_load(
            (const f32x4*)&in[(size_t)row * DDIM + lane * 4]);
        float s = v[0] * v[0] + v[1] * v[1] + v[2] * v[2] + v[3] * v[3];
        #pragma unroll
        for (int o = 32; o > 0; o >>= 1) s += __shfl_down(s, o);
        if (lane == 0) nrm[row] = s;
        half4 h;
        h[0] = (_Float16)v[0]; h[1] = (_Float16)v[1];
        h[2] = (_Float16)v[2]; h[3] = (_Float16)v[3];
        *(half4*)&outh[(size_t)row * DDIM + lane * 4] = h;
    }
    if (blockIdx.x == 0) {                    // re-init every call (graph replay)
        for (int i = threadIdx.x; i < PSI; i += 256) gsum[i] = 0.0f;
    }
}

// ---------- PASS 1: 256x256 tile, m201-style 4-phase/K-tile (R19 verbatim) -
// 8 waves (2M x 4N), 128 KiB LDS, grid 1024 XCD-chunked. Column sums of
// u = exp2(-sqrt(max(x2+s2-2dot,0))*w*log2e) -> atomicAdd into gsum.
__global__ __launch_bounds__(512, 2) void k_gemm_sum(
    const _Float16* __restrict__ Xh, const _Float16* __restrict__ Sh,
    const float* __restrict__ x2, const float* __restrict__ s2,
    const float* __restrict__ w, float* __restrict__ gsum)
{
    __shared__ _Float16 As[2][2][128 * 64];   // 64 KB
    __shared__ _Float16 Bs[2][2][128 * 64];   // 64 KB

    const int tid = threadIdx.x;
    const int wv  = tid >> 6;       // 0..7
    const int wr  = wv >> 2;        // M half (128 rows)
    const int wc  = wv & 3;         // N quarter (64 cols)
    const int l15 = tid & 15;
    const int l4  = (tid & 63) >> 4;

    // XCD swizzle (nwg=1024 divisible by 8 -> bijective)
    const int fid  = blockIdx.x;
    const int wgid = (fid & 7) * 128 + (fid >> 3);
    const int rowb = wgid >> 2;          // 0..255
    const int row0 = rowb * 256;
    const int col0 = (wgid & 3) * 256;

    f32x4 acc[8][4];
    #pragma unroll
    for (int i = 0; i < 8; ++i)
        #pragma unroll
        for (int j = 0; j < 4; ++j) acc[i][j] = (f32x4){0.f, 0.f, 0.f, 0.f};

    const int grow = tid >> 3;           // 0..63
    const int gch  = (tid & 7) ^ (grow & 7);
    const _Float16* gA = Xh + (size_t)(row0 + grow) * DDIM + gch * 8;
    const _Float16* gB = Sh + (size_t)(col0 + grow) * DDIM + gch * 8;

    auto stageA = [&](int kt, int buf, int h) {
        #pragma unroll
        for (int rg = 0; rg < 2; ++rg)
            gload16(gA + (size_t)(h * 128 + rg * 64) * DDIM + kt * 64,
                    &As[buf][h][(rg * 64 + wv * 8) * 64]);
    };
    auto stageB = [&](int kt, int buf, int h) {
        #pragma unroll
        for (int rg = 0; rg < 2; ++rg)
            gload16(gB + (size_t)(h * 128 + rg * 64) * DDIM + kt * 64,
                    &Bs[buf][h][(rg * 64 + wv * 8) * 64]);
    };

    const int qa0 = l15 * 64 + ((l4)     ^ (l15 & 7)) * 8;   // kk=0
    const int qa1 = l15 * 64 + ((4 + l4) ^ (l15 & 7)) * 8;   // kk=1
    const int bof = (wc & 1) * 4096;     // 64 rows into the B half

    half8 a[4][2], blo[2][2], bhi[2][2];
    auto loadA = [&](int cur, int hsel) {
        #pragma unroll
        for (int i = 0; i < 4; ++i) {
            a[i][0] = *(const half8*)&As[cur][wr][(hsel * 4 + i) * 1024 + qa0];
            a[i][1] = *(const half8*)&As[cur][wr][(hsel * 4 + i) * 1024 + qa1];
        }
    };
    auto loadB = [&](int cur, half8 b[2][2], int fnb) {
        #pragma unroll
        for (int jn = 0; jn < 2; ++jn) {
            b[jn][0] = *(const half8*)&Bs[cur][wc >> 1][bof + (fnb + jn) * 1024 + qa0];
            b[jn][1] = *(const half8*)&Bs[cur][wc >> 1][bof + (fnb + jn) * 1024 + qa1];
        }
    };
    auto mfmaQ = [&](half8 b[2][2], int fmb, int fnb) {
        __builtin_amdgcn_s_setprio(1);
        #pragma unroll
        for (int i = 0; i < 4; ++i)
            #pragma unroll
            for (int jn = 0; jn < 2; ++jn)
                #pragma unroll
                for (int kk = 0; kk < 2; ++kk)
                    acc[fmb + i][fnb + jn] = __builtin_amdgcn_mfma_f32_16x16x32_f16(
                        a[i][kk], b[jn][kk], acc[fmb + i][fnb + jn], 0, 0, 0);
        __builtin_amdgcn_s_setprio(0);
    };

    stageA(0, 0, 0); stageA(0, 0, 1); stageB(0, 0, 0); stageB(0, 0, 1);
    asm volatile("s_waitcnt vmcnt(0)\ns_barrier" ::: "memory");

    #pragma unroll
    for (int t = 0; t < 4; ++t) {            // K = 4 x 64
        const int cur = t & 1, nxt = cur ^ 1;
        loadA(cur, 0); loadB(cur, blo, 0);
        if (t < 3) stageA(t + 1, nxt, 0);
        asm volatile("s_barrier" ::: "memory");
        mfmaQ(blo, 0, 0);
        asm volatile("s_barrier" ::: "memory");
        loadB(cur, bhi, 2);
        if (t < 3) stageA(t + 1, nxt, 1);
        asm volatile("s_barrier" ::: "memory");
        mfmaQ(bhi, 0, 2);
        asm volatile("s_barrier" ::: "memory");
        loadA(cur, 1);
        if (t < 3) stageB(t + 1, nxt, 0);
        asm volatile("s_barrier" ::: "memory");
        mfmaQ(bhi, 4, 2);
        asm volatile("s_barrier" ::: "memory");
        if (t < 3) stageB(t + 1, nxt, 1);
        asm volatile("s_barrier" ::: "memory");
        mfmaQ(blo, 4, 0);
        if (t < 3) asm volatile("s_waitcnt vmcnt(0)\ns_barrier" ::: "memory");
    }
    __syncthreads();

    float4 x2r[8];
    #pragma unroll
    for (int fm = 0; fm < 8; ++fm)
        x2r[fm] = *(const float4*)&x2[row0 + wr * 128 + fm * 16 + l4 * 4];

    float* s_sm = (float*)&As[0][0][0];
    if (tid < 256) s_sm[tid] = 0.0f;
    __syncthreads();
    #pragma unroll
    for (int fn = 0; fn < 4; ++fn) {
        const int cl = wc * 64 + fn * 16 + l15;
        const int c  = col0 + cl;
        const float s2c = s2[c], ww2 = w[c] * LOG2E;
        float s = 0.0f;
        #pragma unroll
        for (int fm = 0; fm < 8; ++fm) {
            const float* xr = (const float*)&x2r[fm];
            #pragma unroll
            for (int j = 0; j < 4; ++j) {
                float d2 = xr[j] + s2c - 2.0f * acc[fm][fn][j];
                s += FEXP2(-FSQRT(fmaxf(d2, 0.0f)) * ww2);
            }
        }
        s += __shfl_xor(s, 16);
        s += __shfl_xor(s, 32);
        if (l4 == 0) atomicAdd(&s_sm[cl], s);   // 2 waves (wr) contend
    }
    __syncthreads();
    if (tid < 256) atomicAdd(&gsum[col0 + tid], s_sm[tid]);
}

// ---------- PASS 2: 128x128 tile, BK=64 2-phase dbuf (R17 verbatim) --------
// 64 KB LDS -> 2 blocks/CU: store bursts overlap other blocks' compute.
// out = u * rcp(gsum[c]), scalar NT stores (64B-line coalesced per 16 lanes).
__global__ __launch_bounds__(256) void k_gemm_out(
    const _Float16* __restrict__ Xh, const _Float16* __restrict__ Sh,
    const float* __restrict__ x2, const float* __restrict__ s2,
    const float* __restrict__ w,
    const float* __restrict__ gsum, float* __restrict__ out)
{
    __shared__ _Float16 As[2][128 * 64];   // 2 x 16 KB
    __shared__ _Float16 Bs[2][128 * 64];   // 2 x 16 KB

    const int tid  = threadIdx.x;
    const int wv   = tid >> 6;
    const int wr   = wv >> 1;       // wave row half (0..1)
    const int wc   = wv & 1;        // wave col half (0..1)
    const int l15  = tid & 15;
    const int l4   = (tid & 63) >> 4;

    // XCD swizzle (nwg=4096 divisible by 8 -> bijective)
    const int fid   = blockIdx.x;
    const int wgid  = (fid & 7) * 512 + (fid >> 3);
    const int rowb  = wgid >> 3;            // 0..511
    const int row0  = rowb * 128;
    const int col0  = (wgid & 7) * 128;

    f32x4 acc[4][4];
    #pragma unroll
    for (int i = 0; i < 4; ++i)
        #pragma unroll
        for (int j = 0; j < 4; ++j) acc[i][j] = (f32x4){0.f, 0.f, 0.f, 0.f};

    const int srow = tid >> 3;
    const int skq  = ((tid & 7) ^ (srow & 7)) * 8;
    const _Float16* gAp = Xh + (size_t)(row0 + srow) * DDIM + skq;
    const _Float16* gBp = Sh + (size_t)(col0 + srow) * DDIM + skq;

    auto stage = [&](int k0, int b) {
        _Float16* Ab = &As[b][wv * 512];
        _Float16* Bb = &Bs[b][wv * 512];
        #pragma unroll
        for (int rg = 0; rg < 4; ++rg)
            gload16(gAp + (size_t)(rg * 32) * DDIM + k0, Ab + rg * 2048);
        #pragma unroll
        for (int rg = 0; rg < 4; ++rg)
            gload16(gBp + (size_t)(rg * 32) * DDIM + k0, Bb + rg * 2048);
    };

    auto compute = [&](int b) {
        #pragma unroll
        for (int kk = 0; kk < 2; ++kk) {
            half8 af[4], bf[4];
            #pragma unroll
            for (int f = 0; f < 4; ++f) {
                const int swz = (l15 & 7) << 3;               // halfs
                const int ha = ((wr * 64 + f * 16 + l15) * 64 + kk * 32 + l4 * 8) ^ swz;
                const int hb = ((wc * 64 + f * 16 + l15) * 64 + kk * 32 + l4 * 8) ^ swz;
                af[f] = *(const half8*)&As[b][ha];
                bf[f] = *(const half8*)&Bs[b][hb];
            }
            #pragma unroll
            for (int fm = 0; fm < 4; ++fm)
                #pragma unroll
                for (int fn = 0; fn < 4; ++fn)
                    acc[fm][fn] = __builtin_amdgcn_mfma_f32_16x16x32_f16(
                        af[fm], bf[fn], acc[fm][fn], 0, 0, 0);
        }
    };

    stage(0, 0);
    __syncthreads();
    #pragma unroll
    for (int t = 0; t < 4; ++t) {           // K = 4 x 64
        if (t < 3) stage((t + 1) * 64, (t + 1) & 1);
        compute(t & 1);
        if (t < 3) __syncthreads();
    }

    float4 x2r[4];
    #pragma unroll
    for (int fm = 0; fm < 4; ++fm)
        x2r[fm] = *(const float4*)&x2[row0 + wr * 64 + fm * 16 + l4 * 4];

    #pragma unroll
    for (int fn = 0; fn < 4; ++fn) {
        const int c = col0 + wc * 64 + fn * 16 + l15;
        const float s2c = s2[c], ww2 = w[c] * LOG2E;
        const float rsc = FRCP(gsum[c]);
        #pragma unroll
        for (int fm = 0; fm < 4; ++fm) {
            const float* xr = (const float*)&x2r[fm];
            const int rbase = row0 + wr * 64 + fm * 16 + l4 * 4;
            #pragma unroll
            for (int j = 0; j < 4; ++j) {
                float d2 = xr[j] + s2c - 2.0f * acc[fm][fn][j];
                float u  = FEXP2(-FSQRT(fmaxf(d2, 0.0f)) * ww2) * rsc;
                __builtin_nontemporal_store(u, &out[(size_t)(rbase + j) * PSI + c]);
            }
        }
    }
}

extern "C" void kernel_launch(void* const* d_in, const int* in_sizes, int n_in,
                              void* d_out, int out_size, void* d_ws, size_t ws_size,
                              hipStream_t stream) {
    const float* X = (const float*)d_in[0];
    const float* S = (const float*)d_in[1];
    const float* w = (const float*)d_in[2];
    float* out = (float*)d_out;

    char* ws = (char*)d_ws;
    _Float16* Xh   = (_Float16*)(ws);                  // 33,554,432 B
    _Float16* Sh   = (_Float16*)(ws + 33554432);       //    524,288 B
    float*    x2   = (float*)   (ws + 34078720);       //    262,144 B
    float*    s2   = (float*)   (ws + 34340864);       //      4,096 B
    float*    gsum = (float*)   (ws + 34344960);       //      4,096 B

    k_convert_all<<<dim3(2048), dim3(256), 0, stream>>>(
        X, S, Xh, Sh, x2, s2, gsum);
    k_gemm_sum<<<dim3(1024), dim3(512), 0, stream>>>(
        Xh, Sh, x2, s2, w, gsum);
    k_gemm_out<<<dim3(4096), dim3(256), 0, stream>>>(
        Xh, Sh, x2, s2, w, gsum, out);
}

// Round 22
// 141.028 us; speedup vs baseline: 1.7751x; 1.0477x over previous
//
#include <hip/hip_runtime.h>
#include <hip/hip_bf16.h>
#include <math.h>

#define N_ROWS 65536
#define PSI    1024
#define DDIM   256

typedef _Float16       half8 __attribute__((ext_vector_type(8)));
typedef _Float16       half4 __attribute__((ext_vector_type(4)));
typedef float          f32x4 __attribute__((ext_vector_type(4)));
typedef int            i32x4 __attribute__((ext_vector_type(4)));

#define LOG2E 1.4426950408889634f
#define QSCALE 16.0f          // i8 quant: x8 = round(16x); |x|<5.5sigma -> no clip
#define INV128 0.0078125f     // 2 / (QSCALE^2)

// Raw-instruction transcendentals (~1-2 ulp, negligible vs 3.8e-6 f16 floor).
#if __has_builtin(__builtin_amdgcn_sqrtf)
#define FSQRT(x) __builtin_amdgcn_sqrtf(x)
#else
#define FSQRT(x) sqrtf(x)
#endif
#if __has_builtin(__builtin_amdgcn_exp2f)
#define FEXP2(x) __builtin_amdgcn_exp2f(x)
#else
#define FEXP2(x) exp2f(x)
#endif
#if __has_builtin(__builtin_amdgcn_rcpf)
#define FRCP(x) __builtin_amdgcn_rcpf(x)
#else
#define FRCP(x) (1.0f / (x))
#endif

// ---------- async global->LDS, 16B per lane ----------
__device__ __forceinline__ void gload16(const void* g, void* l) {
    __builtin_amdgcn_global_load_lds(
        (const __attribute__((address_space(1))) unsigned int*)g,
        (__attribute__((address_space(3))) unsigned int*)l, 16, 0, 0);
}

// ---------- fused convert (X,S) -> f16 + i8 + row norms + gsum init --------
__global__ __launch_bounds__(256) void k_convert_all(
    const float* __restrict__ X, const float* __restrict__ S,
    _Float16* __restrict__ Xh, _Float16* __restrict__ Sh,
    char* __restrict__ Xi8, char* __restrict__ Si8,
    float* __restrict__ x2, float* __restrict__ s2,
    float* __restrict__ gsum)
{
    const int wib  = threadIdx.x >> 6;
    const int lane = threadIdx.x & 63;
    for (int u = blockIdx.x; u < 16640; u += 2048) {
        const float* in; _Float16* outh; char* outi; float* nrm; int row;
        if (u < 16384) { in = X; outh = Xh; outi = Xi8; nrm = x2; row = u * 4 + wib; }
        else { in = S; outh = Sh; outi = Si8; nrm = s2; row = (u - 16384) * 4 + wib; }
        const f32x4 v = __builtin_nontemporal_load(
            (const f32x4*)&in[(size_t)row * DDIM + lane * 4]);
        float s = v[0] * v[0] + v[1] * v[1] + v[2] * v[2] + v[3] * v[3];
        #pragma unroll
        for (int o = 32; o > 0; o >>= 1) s += __shfl_down(s, o);
        if (lane == 0) nrm[row] = s;
        half4 h;
        h[0] = (_Float16)v[0]; h[1] = (_Float16)v[1];
        h[2] = (_Float16)v[2]; h[3] = (_Float16)v[3];
        *(half4*)&outh[(size_t)row * DDIM + lane * 4] = h;
        char4 q;
        #pragma unroll
        for (int i = 0; i < 4; ++i) {
            float t = fminf(fmaxf(v[i] * QSCALE, -127.0f), 127.0f);
            ((char*)&q)[i] = (char)__float2int_rn(t);
        }
        *(char4*)&outi[(size_t)row * DDIM + lane * 4] = q;
    }
    if (blockIdx.x == 0) {                    // re-init every call (graph replay)
        for (int i = threadIdx.x; i < PSI; i += 256) gsum[i] = 0.0f;
    }
}

// ---------- PASS 1: i8 MFMA, 256x256 tile, K=256 in two 128B halves --------
// Sums tolerate quantization: per-row u error ~1.8% averages to ~0.02% on
// gsum over 65536 rows (bias dm^2/2 + random/sqrt(N)) -> output impact
// <3e-7, invisible vs the 3.8e-6 f16 floor. Int dot is EXACT (<=4.1e6).
// mfma_i32_16x16x64_i8: 2x f16 MFMA rate, half the staging bytes.
// 8 waves (2M x 4N), LDS 2x(32+32) KB dbuf, R6-proven 2-phase loop.
// Swizzle both-sides: 128B rows = 8x16B slots, slot ^= row&7 (pre-swizzled
// global chunk on stage, XOR'd ds_read) -- identical geometry to f16 case.
// d2 = x2 + s2 - dot*INV128; u = exp2(-sqrt(max(d2,0))*w*log2e).
__global__ __launch_bounds__(512, 2) void k_gemm_sum_i8(
    const char* __restrict__ Xi8, const char* __restrict__ Si8,
    const float* __restrict__ x2, const float* __restrict__ s2,
    const float* __restrict__ w, float* __restrict__ gsum)
{
    __shared__ __align__(16) char As[2][256 * 128];   // 2 x 32 KB
    __shared__ __align__(16) char Bs[2][256 * 128];   // 2 x 32 KB

    const int tid = threadIdx.x;
    const int wv  = tid >> 6;       // 0..7
    const int wr  = wv >> 2;        // M half (128 rows)
    const int wc  = wv & 3;         // N quarter (64 cols)
    const int l15 = tid & 15;
    const int l4  = (tid & 63) >> 4;

    // XCD swizzle (nwg=1024 divisible by 8 -> bijective)
    const int fid  = blockIdx.x;
    const int wgid = (fid & 7) * 128 + (fid >> 3);
    const int rowb = wgid >> 2;          // 0..255
    const int row0 = rowb * 256;
    const int col0 = (wgid & 3) * 256;

    i32x4 acc[8][4];
    #pragma unroll
    for (int i = 0; i < 8; ++i)
        #pragma unroll
        for (int j = 0; j < 4; ++j) acc[i][j] = (i32x4){0, 0, 0, 0};

    // staging: thread covers row tid>>3 of each 64-row group; global 16B
    // chunk pre-swizzled gch = (tid&7)^(grow&7). 8 lanes cover one 128B half-row.
    const int grow = tid >> 3;           // 0..63
    const int gch  = (tid & 7) ^ (grow & 7);
    const char* gA = Xi8 + (size_t)(row0 + grow) * DDIM + gch * 16;
    const char* gB = Si8 + (size_t)(col0 + grow) * DDIM + gch * 16;

    auto stageA = [&](int h, int buf) {      // h = K-half (0,1), 128 B each
        #pragma unroll
        for (int rg = 0; rg < 4; ++rg)
            gload16(gA + (size_t)(rg * 64) * DDIM + h * 128,
                    &As[buf][rg * 8192 + wv * 1024]);
    };
    auto stageB = [&](int h, int buf) {
        #pragma unroll
        for (int rg = 0; rg < 4; ++rg)
            gload16(gB + (size_t)(rg * 64) * DDIM + h * 128,
                    &Bs[buf][rg * 8192 + wv * 1024]);
    };

    auto compute = [&](int buf) {
        #pragma unroll
        for (int tt = 0; tt < 2; ++tt) {     // 2 K-steps of 64 per half
            const int slot = (l4 + 4 * tt) ^ (l15 & 7);
            i32x4 af[8], bf[4];
            #pragma unroll
            for (int f = 0; f < 8; ++f)
                af[f] = *(const i32x4*)&As[buf][(wr * 128 + f * 16 + l15) * 128 + slot * 16];
            #pragma unroll
            for (int f = 0; f < 4; ++f)
                bf[f] = *(const i32x4*)&Bs[buf][(wc * 64 + f * 16 + l15) * 128 + slot * 16];
            __builtin_amdgcn_s_setprio(1);
            #pragma unroll
            for (int fm = 0; fm < 8; ++fm)
                #pragma unroll
                for (int fn = 0; fn < 4; ++fn)
                    acc[fm][fn] = __builtin_amdgcn_mfma_i32_16x16x64_i8(
                        af[fm], bf[fn], acc[fm][fn], 0, 0, 0);
            __builtin_amdgcn_s_setprio(0);
        }
    };

    stageA(0, 0); stageB(0, 0);
    __syncthreads();
    stageA(1, 1); stageB(1, 1);
    compute(0);
    __syncthreads();
    compute(1);
    __syncthreads();

    // ---- epilogue: column sums of u ----
    float4 x2r[8];
    #pragma unroll
    for (int fm = 0; fm < 8; ++fm)
        x2r[fm] = *(const float4*)&x2[row0 + wr * 128 + fm * 16 + l4 * 4];

    float* s_sm = (float*)&As[0][0];
    if (tid < 256) s_sm[tid] = 0.0f;
    __syncthreads();
    #pragma unroll
    for (int fn = 0; fn < 4; ++fn) {
        const int cl = wc * 64 + fn * 16 + l15;
        const int c  = col0 + cl;
        const float s2c = s2[c], ww2 = w[c] * LOG2E;
        float s = 0.0f;
        #pragma unroll
        for (int fm = 0; fm < 8; ++fm) {
            const float* xr = (const float*)&x2r[fm];
            #pragma unroll
            for (int j = 0; j < 4; ++j) {
                float d2 = xr[j] + s2c - (float)acc[fm][fn][j] * INV128;
                s += FEXP2(-FSQRT(fmaxf(d2, 0.0f)) * ww2);
            }
        }
        s += __shfl_xor(s, 16);
        s += __shfl_xor(s, 32);
        if (l4 == 0) atomicAdd(&s_sm[cl], s);   // 2 waves (wr) contend
    }
    __syncthreads();
    if (tid < 256) atomicAdd(&gsum[col0 + tid], s_sm[tid]);
}

// ---------- PASS 2: f16 MFMA, 128x128 tile, BK=64 2-phase dbuf (proven) ----
// out = u * rcp(gsum[c]), scalar NT stores (64B-line coalesced per 16 lanes).
__global__ __launch_bounds__(256) void k_gemm_out(
    const _Float16* __restrict__ Xh, const _Float16* __restrict__ Sh,
    const float* __restrict__ x2, const float* __restrict__ s2,
    const float* __restrict__ w,
    const float* __restrict__ gsum, float* __restrict__ out)
{
    __shared__ _Float16 As[2][128 * 64];   // 2 x 16 KB
    __shared__ _Float16 Bs[2][128 * 64];   // 2 x 16 KB

    const int tid  = threadIdx.x;
    const int wv   = tid >> 6;
    const int wr   = wv >> 1;       // wave row half (0..1)
    const int wc   = wv & 1;        // wave col half (0..1)
    const int l15  = tid & 15;
    const int l4   = (tid & 63) >> 4;

    // XCD swizzle (nwg=4096 divisible by 8 -> bijective)
    const int fid   = blockIdx.x;
    const int wgid  = (fid & 7) * 512 + (fid >> 3);
    const int rowb  = wgid >> 3;            // 0..511
    const int row0  = rowb * 128;
    const int col0  = (wgid & 7) * 128;

    f32x4 acc[4][4];
    #pragma unroll
    for (int i = 0; i < 4; ++i)
        #pragma unroll
        for (int j = 0; j < 4; ++j) acc[i][j] = (f32x4){0.f, 0.f, 0.f, 0.f};

    const int srow = tid >> 3;
    const int skq  = ((tid & 7) ^ (srow & 7)) * 8;
    const _Float16* gAp = Xh + (size_t)(row0 + srow) * DDIM + skq;
    const _Float16* gBp = Sh + (size_t)(col0 + srow) * DDIM + skq;

    auto stage = [&](int k0, int b) {
        _Float16* Ab = &As[b][wv * 512];
        _Float16* Bb = &Bs[b][wv * 512];
        #pragma unroll
        for (int rg = 0; rg < 4; ++rg)
            gload16(gAp + (size_t)(rg * 32) * DDIM + k0, Ab + rg * 2048);
        #pragma unroll
        for (int rg = 0; rg < 4; ++rg)
            gload16(gBp + (size_t)(rg * 32) * DDIM + k0, Bb + rg * 2048);
    };

    auto compute = [&](int b) {
        #pragma unroll
        for (int kk = 0; kk < 2; ++kk) {
            half8 af[4], bf[4];
            #pragma unroll
            for (int f = 0; f < 4; ++f) {
                const int swz = (l15 & 7) << 3;               // halfs
                const int ha = ((wr * 64 + f * 16 + l15) * 64 + kk * 32 + l4 * 8) ^ swz;
                const int hb = ((wc * 64 + f * 16 + l15) * 64 + kk * 32 + l4 * 8) ^ swz;
                af[f] = *(const half8*)&As[b][ha];
                bf[f] = *(const half8*)&Bs[b][hb];
            }
            #pragma unroll
            for (int fm = 0; fm < 4; ++fm)
                #pragma unroll
                for (int fn = 0; fn < 4; ++fn)
                    acc[fm][fn] = __builtin_amdgcn_mfma_f32_16x16x32_f16(
                        af[fm], bf[fn], acc[fm][fn], 0, 0, 0);
        }
    };

    stage(0, 0);
    __syncthreads();
    #pragma unroll
    for (int t = 0; t < 4; ++t) {           // K = 4 x 64
        if (t < 3) stage((t + 1) * 64, (t + 1) & 1);
        compute(t & 1);
        if (t < 3) __syncthreads();
    }

    float4 x2r[4];
    #pragma unroll
    for (int fm = 0; fm < 4; ++fm)
        x2r[fm] = *(const float4*)&x2[row0 + wr * 64 + fm * 16 + l4 * 4];

    #pragma unroll
    for (int fn = 0; fn < 4; ++fn) {
        const int c = col0 + wc * 64 + fn * 16 + l15;
        const float s2c = s2[c], ww2 = w[c] * LOG2E;
        const float rsc = FRCP(gsum[c]);
        #pragma unroll
        for (int fm = 0; fm < 4; ++fm) {
            const float* xr = (const float*)&x2r[fm];
            const int rbase = row0 + wr * 64 + fm * 16 + l4 * 4;
            #pragma unroll
            for (int j = 0; j < 4; ++j) {
                float d2 = xr[j] + s2c - 2.0f * acc[fm][fn][j];
                float u  = FEXP2(-FSQRT(fmaxf(d2, 0.0f)) * ww2) * rsc;
                __builtin_nontemporal_store(u, &out[(size_t)(rbase + j) * PSI + c]);
            }
        }
    }
}

extern "C" void kernel_launch(void* const* d_in, const int* in_sizes, int n_in,
                              void* d_out, int out_size, void* d_ws, size_t ws_size,
                              hipStream_t stream) {
    const float* X = (const float*)d_in[0];
    const float* S = (const float*)d_in[1];
    const float* w = (const float*)d_in[2];
    float* out = (float*)d_out;

    char* ws = (char*)d_ws;
    _Float16* Xh   = (_Float16*)(ws);                  // 33,554,432 B
    _Float16* Sh   = (_Float16*)(ws + 33554432);       //    524,288 B
    float*    x2   = (float*)   (ws + 34078720);       //    262,144 B
    float*    s2   = (float*)   (ws + 34340864);       //      4,096 B
    float*    gsum = (float*)   (ws + 34344960);       //      4,096 B
    char*     Xi8  = (char*)    (ws + 34349056);       // 16,777,216 B
    char*     Si8  = (char*)    (ws + 51126272);       //    262,144 B

    k_convert_all<<<dim3(2048), dim3(256), 0, stream>>>(
        X, S, Xh, Sh, Xi8, Si8, x2, s2, gsum);
    k_gemm_sum_i8<<<dim3(1024), dim3(512), 0, stream>>>(
        Xi8, Si8, x2, s2, w, gsum);
    k_gemm_out<<<dim3(4096), dim3(256), 0, stream>>>(
        Xh, Sh, x2, s2, w, gsum, out);
}

// Round 23
// 132.248 us; speedup vs baseline: 1.8929x; 1.0664x over previous
//
#include <hip/hip_runtime.h>
#include <hip/hip_bf16.h>
#include <math.h>

#define N_ROWS 65536
#define PSI    1024
#define DDIM   256

typedef _Float16       half8 __attribute__((ext_vector_type(8)));
typedef _Float16       half4 __attribute__((ext_vector_type(4)));
typedef float          f32x4 __attribute__((ext_vector_type(4)));
typedef int            i32x4 __attribute__((ext_vector_type(4)));

#define LOG2E 1.4426950408889634f
#define QSCALE 16.0f          // i8 quant: x8 = round(16x); |x|<5.5sigma -> no clip
#define INV128 0.0078125f     // 2 / (QSCALE^2)

// Raw-instruction transcendentals (~1-2 ulp, negligible vs 3.8e-6 f16 floor).
#if __has_builtin(__builtin_amdgcn_sqrtf)
#define FSQRT(x) __builtin_amdgcn_sqrtf(x)
#else
#define FSQRT(x) sqrtf(x)
#endif
#if __has_builtin(__builtin_amdgcn_exp2f)
#define FEXP2(x) __builtin_amdgcn_exp2f(x)
#else
#define FEXP2(x) exp2f(x)
#endif
#if __has_builtin(__builtin_amdgcn_rcpf)
#define FRCP(x) __builtin_amdgcn_rcpf(x)
#else
#define FRCP(x) (1.0f / (x))
#endif

// ---------- async global->LDS, 16B per lane ----------
__device__ __forceinline__ void gload16(const void* g, void* l) {
    __builtin_amdgcn_global_load_lds(
        (const __attribute__((address_space(1))) unsigned int*)g,
        (__attribute__((address_space(3))) unsigned int*)l, 16, 0, 0);
}

// ---------- fused convert (X,S) -> f16 + i8 + row norms + gsum init --------
__global__ __launch_bounds__(256) void k_convert_all(
    const float* __restrict__ X, const float* __restrict__ S,
    _Float16* __restrict__ Xh, _Float16* __restrict__ Sh,
    char* __restrict__ Xi8, char* __restrict__ Si8,
    float* __restrict__ x2, float* __restrict__ s2,
    float* __restrict__ gsum)
{
    const int wib  = threadIdx.x >> 6;
    const int lane = threadIdx.x & 63;
    for (int u = blockIdx.x; u < 16640; u += 2048) {
        const float* in; _Float16* outh; char* outi; float* nrm; int row;
        if (u < 16384) { in = X; outh = Xh; outi = Xi8; nrm = x2; row = u * 4 + wib; }
        else { in = S; outh = Sh; outi = Si8; nrm = s2; row = (u - 16384) * 4 + wib; }
        const f32x4 v = __builtin_nontemporal_load(
            (const f32x4*)&in[(size_t)row * DDIM + lane * 4]);
        float s = v[0] * v[0] + v[1] * v[1] + v[2] * v[2] + v[3] * v[3];
        #pragma unroll
        for (int o = 32; o > 0; o >>= 1) s += __shfl_down(s, o);
        if (lane == 0) nrm[row] = s;
        half4 h;
        h[0] = (_Float16)v[0]; h[1] = (_Float16)v[1];
        h[2] = (_Float16)v[2]; h[3] = (_Float16)v[3];
        *(half4*)&outh[(size_t)row * DDIM + lane * 4] = h;
        char4 q;
        #pragma unroll
        for (int i = 0; i < 4; ++i) {
            float t = fminf(fmaxf(v[i] * QSCALE, -127.0f), 127.0f);
            ((char*)&q)[i] = (char)__float2int_rn(t);
        }
        *(char4*)&outi[(size_t)row * DDIM + lane * 4] = q;
    }
    if (blockIdx.x == 0) {                    // re-init every call (graph replay)
        for (int i = threadIdx.x; i < PSI; i += 256) gsum[i] = 0.0f;
    }
}

// ---------- PASS 1: i8 MFMA, 256x256 tile, K=256 in two 128B halves --------
// Sums tolerate quantization: per-row u error ~1.8% averages to ~0.02% on
// gsum over 65536 rows -> output impact <3e-7 (verified: absmax unchanged).
// mfma_i32_16x16x64_i8: 2x f16 MFMA rate, half the staging bytes.
__global__ __launch_bounds__(512, 2) void k_gemm_sum_i8(
    const char* __restrict__ Xi8, const char* __restrict__ Si8,
    const float* __restrict__ x2, const float* __restrict__ s2,
    const float* __restrict__ w, float* __restrict__ gsum)
{
    __shared__ __align__(16) char As[2][256 * 128];   // 2 x 32 KB
    __shared__ __align__(16) char Bs[2][256 * 128];   // 2 x 32 KB

    const int tid = threadIdx.x;
    const int wv  = tid >> 6;       // 0..7
    const int wr  = wv >> 2;        // M half (128 rows)
    const int wc  = wv & 3;         // N quarter (64 cols)
    const int l15 = tid & 15;
    const int l4  = (tid & 63) >> 4;

    // XCD swizzle (nwg=1024 divisible by 8 -> bijective)
    const int fid  = blockIdx.x;
    const int wgid = (fid & 7) * 128 + (fid >> 3);
    const int rowb = wgid >> 2;          // 0..255
    const int row0 = rowb * 256;
    const int col0 = (wgid & 3) * 256;

    i32x4 acc[8][4];
    #pragma unroll
    for (int i = 0; i < 8; ++i)
        #pragma unroll
        for (int j = 0; j < 4; ++j) acc[i][j] = (i32x4){0, 0, 0, 0};

    const int grow = tid >> 3;           // 0..63
    const int gch  = (tid & 7) ^ (grow & 7);
    const char* gA = Xi8 + (size_t)(row0 + grow) * DDIM + gch * 16;
    const char* gB = Si8 + (size_t)(col0 + grow) * DDIM + gch * 16;

    auto stageA = [&](int h, int buf) {      // h = K-half (0,1), 128 B each
        #pragma unroll
        for (int rg = 0; rg < 4; ++rg)
            gload16(gA + (size_t)(rg * 64) * DDIM + h * 128,
                    &As[buf][rg * 8192 + wv * 1024]);
    };
    auto stageB = [&](int h, int buf) {
        #pragma unroll
        for (int rg = 0; rg < 4; ++rg)
            gload16(gB + (size_t)(rg * 64) * DDIM + h * 128,
                    &Bs[buf][rg * 8192 + wv * 1024]);
    };

    auto compute = [&](int buf) {
        #pragma unroll
        for (int tt = 0; tt < 2; ++tt) {     // 2 K-steps of 64 per half
            const int slot = (l4 + 4 * tt) ^ (l15 & 7);
            i32x4 af[8], bf[4];
            #pragma unroll
            for (int f = 0; f < 8; ++f)
                af[f] = *(const i32x4*)&As[buf][(wr * 128 + f * 16 + l15) * 128 + slot * 16];
            #pragma unroll
            for (int f = 0; f < 4; ++f)
                bf[f] = *(const i32x4*)&Bs[buf][(wc * 64 + f * 16 + l15) * 128 + slot * 16];
            __builtin_amdgcn_s_setprio(1);
            #pragma unroll
            for (int fm = 0; fm < 8; ++fm)
                #pragma unroll
                for (int fn = 0; fn < 4; ++fn)
                    acc[fm][fn] = __builtin_amdgcn_mfma_i32_16x16x64_i8(
                        af[fm], bf[fn], acc[fm][fn], 0, 0, 0);
            __builtin_amdgcn_s_setprio(0);
        }
    };

    stageA(0, 0); stageB(0, 0);
    __syncthreads();
    stageA(1, 1); stageB(1, 1);
    compute(0);
    __syncthreads();
    compute(1);
    __syncthreads();

    // ---- epilogue: column sums of u ----
    float4 x2r[8];
    #pragma unroll
    for (int fm = 0; fm < 8; ++fm)
        x2r[fm] = *(const float4*)&x2[row0 + wr * 128 + fm * 16 + l4 * 4];

    float* s_sm = (float*)&As[0][0];
    if (tid < 256) s_sm[tid] = 0.0f;
    __syncthreads();
    #pragma unroll
    for (int fn = 0; fn < 4; ++fn) {
        const int cl = wc * 64 + fn * 16 + l15;
        const int c  = col0 + cl;
        const float s2c = s2[c], ww2 = w[c] * LOG2E;
        float s = 0.0f;
        #pragma unroll
        for (int fm = 0; fm < 8; ++fm) {
            const float* xr = (const float*)&x2r[fm];
            #pragma unroll
            for (int j = 0; j < 4; ++j) {
                float d2 = xr[j] + s2c - (float)acc[fm][fn][j] * INV128;
                s += FEXP2(-FSQRT(fmaxf(d2, 0.0f)) * ww2);
            }
        }
        s += __shfl_xor(s, 16);
        s += __shfl_xor(s, 32);
        if (l4 == 0) atomicAdd(&s_sm[cl], s);   // 2 waves (wr) contend
    }
    __syncthreads();
    if (tid < 256) atomicAdd(&gsum[col0 + tid], s_sm[tid]);
}

// ---------- PASS 2: f16 MFMA, 128x128 tile, BK=64 2-phase dbuf -------------
// out = u * rcp(gsum[c]) with PLAIN CACHED stores (NT removed): the harness
// fill kernel shows plain stores sustain 7.0 TB/s vs ~5 TB/s measured on our
// NT streams; L2 pollution is cheap here (B-panel 0.5MB/XCD, X streams once).
__global__ __launch_bounds__(256) void k_gemm_out(
    const _Float16* __restrict__ Xh, const _Float16* __restrict__ Sh,
    const float* __restrict__ x2, const float* __restrict__ s2,
    const float* __restrict__ w,
    const float* __restrict__ gsum, float* __restrict__ out)
{
    __shared__ _Float16 As[2][128 * 64];   // 2 x 16 KB
    __shared__ _Float16 Bs[2][128 * 64];   // 2 x 16 KB

    const int tid  = threadIdx.x;
    const int wv   = tid >> 6;
    const int wr   = wv >> 1;       // wave row half (0..1)
    const int wc   = wv & 1;        // wave col half (0..1)
    const int l15  = tid & 15;
    const int l4   = (tid & 63) >> 4;

    // XCD swizzle (nwg=4096 divisible by 8 -> bijective)
    const int fid   = blockIdx.x;
    const int wgid  = (fid & 7) * 512 + (fid >> 3);
    const int rowb  = wgid >> 3;            // 0..511
    const int row0  = rowb * 128;
    const int col0  = (wgid & 7) * 128;

    f32x4 acc[4][4];
    #pragma unroll
    for (int i = 0; i < 4; ++i)
        #pragma unroll
        for (int j = 0; j < 4; ++j) acc[i][j] = (f32x4){0.f, 0.f, 0.f, 0.f};

    const int srow = tid >> 3;
    const int skq  = ((tid & 7) ^ (srow & 7)) * 8;
    const _Float16* gAp = Xh + (size_t)(row0 + srow) * DDIM + skq;
    const _Float16* gBp = Sh + (size_t)(col0 + srow) * DDIM + skq;

    auto stage = [&](int k0, int b) {
        _Float16* Ab = &As[b][wv * 512];
        _Float16* Bb = &Bs[b][wv * 512];
        #pragma unroll
        for (int rg = 0; rg < 4; ++rg)
            gload16(gAp + (size_t)(rg * 32) * DDIM + k0, Ab + rg * 2048);
        #pragma unroll
        for (int rg = 0; rg < 4; ++rg)
            gload16(gBp + (size_t)(rg * 32) * DDIM + k0, Bb + rg * 2048);
    };

    auto compute = [&](int b) {
        #pragma unroll
        for (int kk = 0; kk < 2; ++kk) {
            half8 af[4], bf[4];
            #pragma unroll
            for (int f = 0; f < 4; ++f) {
                const int swz = (l15 & 7) << 3;               // halfs
                const int ha = ((wr * 64 + f * 16 + l15) * 64 + kk * 32 + l4 * 8) ^ swz;
                const int hb = ((wc * 64 + f * 16 + l15) * 64 + kk * 32 + l4 * 8) ^ swz;
                af[f] = *(const half8*)&As[b][ha];
                bf[f] = *(const half8*)&Bs[b][hb];
            }
            #pragma unroll
            for (int fm = 0; fm < 4; ++fm)
                #pragma unroll
                for (int fn = 0; fn < 4; ++fn)
                    acc[fm][fn] = __builtin_amdgcn_mfma_f32_16x16x32_f16(
                        af[fm], bf[fn], acc[fm][fn], 0, 0, 0);
        }
    };

    stage(0, 0);
    __syncthreads();
    #pragma unroll
    for (int t = 0; t < 4; ++t) {           // K = 4 x 64
        if (t < 3) stage((t + 1) * 64, (t + 1) & 1);
        compute(t & 1);
        if (t < 3) __syncthreads();
    }

    float4 x2r[4];
    #pragma unroll
    for (int fm = 0; fm < 4; ++fm)
        x2r[fm] = *(const float4*)&x2[row0 + wr * 64 + fm * 16 + l4 * 4];

    #pragma unroll
    for (int fn = 0; fn < 4; ++fn) {
        const int c = col0 + wc * 64 + fn * 16 + l15;
        const float s2c = s2[c], ww2 = w[c] * LOG2E;
        const float rsc = FRCP(gsum[c]);
        #pragma unroll
        for (int fm = 0; fm < 4; ++fm) {
            const float* xr = (const float*)&x2r[fm];
            const int rbase = row0 + wr * 64 + fm * 16 + l4 * 4;
            #pragma unroll
            for (int j = 0; j < 4; ++j) {
                float d2 = xr[j] + s2c - 2.0f * acc[fm][fn][j];
                float u  = FEXP2(-FSQRT(fmaxf(d2, 0.0f)) * ww2) * rsc;
                out[(size_t)(rbase + j) * PSI + c] = u;   // plain cached store
            }
        }
    }
}

extern "C" void kernel_launch(void* const* d_in, const int* in_sizes, int n_in,
                              void* d_out, int out_size, void* d_ws, size_t ws_size,
                              hipStream_t stream) {
    const float* X = (const float*)d_in[0];
    const float* S = (const float*)d_in[1];
    const float* w = (const float*)d_in[2];
    float* out = (float*)d_out;

    char* ws = (char*)d_ws;
    _Float16* Xh   = (_Float16*)(ws);                  // 33,554,432 B
    _Float16* Sh   = (_Float16*)(ws + 33554432);       //    524,288 B
    float*    x2   = (float*)   (ws + 34078720);       //    262,144 B
    float*    s2   = (float*)   (ws + 34340864);       //      4,096 B
    float*    gsum = (float*)   (ws + 34344960);       //      4,096 B
    char*     Xi8  = (char*)    (ws + 34349056);       // 16,777,216 B
    char*     Si8  = (char*)    (ws + 51126272);       //    262,144 B

    k_convert_all<<<dim3(2048), dim3(256), 0, stream>>>(
        X, S, Xh, Sh, Xi8, Si8, x2, s2, gsum);
    k_gemm_sum_i8<<<dim3(1024), dim3(512), 0, stream>>>(
        Xi8, Si8, x2, s2, w, gsum);
    k_gemm_out<<<dim3(4096), dim3(256), 0, stream>>>(
        Xh, Sh, x2, s2, w, gsum, out);
}